// Round 2
// baseline (55.643 us; speedup 1.0000x reference)
//
#include <hip/hip_runtime.h>

// ResonantHTT embedding via two pair tables:
//   T[p01][u][b] = sum_a core0[i0,0,a,D0]*cos(phase[a]) * core1[i1,a,b,d1]
//       p01 = i0*16+i1, u = D0*8+d1   -> 256 x 64 x 16 f32 = 1 MB
//   F[p23][v][b] = sum_c core2[i2,b,c,d2] * core3[i3,c,0,d3]
//       p23 = i2*16+i3, v = d2*4+d3   -> 256 x 16 x 16 f32 = 256 KB
// Per token: out[n, u*16+v] = sum_b T[p01][u][b] * F[p23][v][b]
//   (u*16+v == D0*128 + d1*16 + d2*4 + d3, the reference layout)

__global__ __launch_bounds__(256) void k_tables(
    const float* __restrict__ core0, const float* __restrict__ core1,
    const float* __restrict__ core2, const float* __restrict__ core3,
    const float* __restrict__ phase,
    float* __restrict__ T, float* __restrict__ F)
{
  const int gid = blockIdx.x * 256 + threadIdx.x;
  if (blockIdx.x < 1024) {
    // ---- T part: 262144 outputs, one per thread ----
    const int p01 = gid >> 10, r = gid & 1023;
    const int u = r >> 4, b = r & 15;
    const int D0 = u >> 3, d1 = u & 7;
    const int i0 = p01 >> 4, i1 = p01 & 15;
    const int lane = threadIdx.x & 63;
    // each 16-lane segment computes cos(phase[0..15]) once, shuffles per a
    const float cown = cosf(phase[lane & 15]);
    const float* c0 = core0 + i0 * 128 + D0;          // [a] stride 8
    const float* c1 = core1 + i1 * 2048 + b * 8 + d1; // [a] stride 128
    float acc = 0.f;
    #pragma unroll
    for (int a = 0; a < 16; ++a) {
      const float ca = __shfl(cown, a, 16);
      acc += c0[a * 8] * ca * c1[a * 128];
    }
    T[p01 * 1024 + u * 16 + b] = acc;
  } else {
    // ---- F part: 65536 outputs, one per thread ----
    const int o = gid - 262144;
    const int p23 = o >> 8, r = o & 255;
    const int v = r >> 4, b = r & 15;
    const int d2 = v >> 2, d3 = v & 3;
    const int i2 = p23 >> 4, i3 = p23 & 15;
    const float* c2 = core2 + i2 * 1024 + b * 64 + d2; // [c] stride 4
    const float* c3 = core3 + i3 * 64 + d3;            // [c] stride 4
    float acc = 0.f;
    #pragma unroll
    for (int c = 0; c < 16; ++c)
      acc += c2[c * 4] * c3[c * 4];
    F[p23 * 256 + v * 16 + b] = acc;
  }
}

__global__ __launch_bounds__(256) void k_out2(
    const int* __restrict__ ids, const float* __restrict__ T,
    const float* __restrict__ F, float* __restrict__ out)
{
  const int wave = threadIdx.x >> 6, lane = threadIdx.x & 63;
  const int n = blockIdx.x * 4 + wave;            // one token per wave
  const int id = ids[n];
  const int p01 = id >> 8, p23 = id & 255;
  const int v = lane & 15, ug = lane >> 4;        // lane = (u-group, v)

  // F row for this lane's v: 16 b-values in 4 float4s (64B-aligned)
  const float* Fp = F + p23 * 256 + v * 16;
  const float4 f0 = *reinterpret_cast<const float4*>(Fp);
  const float4 f1 = *reinterpret_cast<const float4*>(Fp + 4);
  const float4 f2 = *reinterpret_cast<const float4*>(Fp + 8);
  const float4 f3 = *reinterpret_cast<const float4*>(Fp + 12);

  const float* Tp = T + p01 * 1024 + ug * 256;    // this group's 16 u-rows
  float* op = out + (size_t)n * 1024 + ug * 256 + v;

  #pragma unroll
  for (int k = 0; k < 16; ++k) {                  // u = ug*16 + k
    const float4 t0 = *reinterpret_cast<const float4*>(Tp + k * 16);
    const float4 t1 = *reinterpret_cast<const float4*>(Tp + k * 16 + 4);
    const float4 t2 = *reinterpret_cast<const float4*>(Tp + k * 16 + 8);
    const float4 t3 = *reinterpret_cast<const float4*>(Tp + k * 16 + 12);
    const float acc =
        t0.x * f0.x + t0.y * f0.y + t0.z * f0.z + t0.w * f0.w +
        t1.x * f1.x + t1.y * f1.y + t1.z * f1.z + t1.w * f1.w +
        t2.x * f2.x + t2.y * f2.y + t2.z * f2.z + t2.w * f2.w +
        t3.x * f3.x + t3.y * f3.y + t3.z * f3.z + t3.w * f3.w;
    // lanes of one u-group write 64 contiguous bytes; 4 groups -> 4 full
    // 64B lines per store instruction (fully coalesced)
    op[k * 16] = acc;
  }
}

extern "C" void kernel_launch(void* const* d_in, const int* in_sizes, int n_in,
                              void* d_out, int out_size, void* d_ws, size_t ws_size,
                              hipStream_t stream) {
  const int*   ids   = (const int*)  d_in[0];
  const float* core0 = (const float*)d_in[1];
  const float* core1 = (const float*)d_in[2];
  const float* core2 = (const float*)d_in[3];
  const float* core3 = (const float*)d_in[4];
  const float* phase = (const float*)d_in[5];
  float* out = (float*)d_out;

  float* Tt = (float*)d_ws;                    // 1 MB
  float* Ft = (float*)d_ws + 256 * 1024;       // 256 KB

  const int tokens = in_sizes[0];              // 16384
  hipLaunchKernelGGL(k_tables, dim3(1280), dim3(256), 0, stream,
                     core0, core1, core2, core3, phase, Tt, Ft);
  hipLaunchKernelGGL(k_out2, dim3(tokens / 4), dim3(256), 0, stream,
                     ids, Tt, Ft, out);
}

// Round 4
// 30.053 us; speedup vs baseline: 1.8515x; 1.8515x over previous
//
#include <hip/hip_runtime.h>

// ResonantHTT embedding via two pair tables (b-major layout):
//   T[p01][b][u] = sum_a core0[i0,0,a,D0]*cos(phase[a]) * core1[i1,a,b,d1]
//       p01 = i0*16+i1, u = D0*8+d1   -> 256 x 16 x 64 f32 = 1 MB
//   F[p23][b][v] = sum_c core2[i2,b,c,d2] * core3[i3,c,0,d3]
//       p23 = i2*16+i3, v = d2*4+d3   -> 256 x 16 x 16 f32 = 256 KB
// Per token: out[n, u*16+v] = sum_b T[p01][b][u] * F[p23][b][v]
// k_out: lane owns a 4x4 (u,v) tile -> 512 B operands/lane (the floor),
// all loads coalesced float4, 4 coalesced 1KB nontemporal stores.

typedef float f32x4 __attribute__((ext_vector_type(4)));

__global__ __launch_bounds__(256) void k_tables(
    const float* __restrict__ core0, const float* __restrict__ core1,
    const float* __restrict__ core2, const float* __restrict__ core3,
    const float* __restrict__ phase,
    float* __restrict__ T, float* __restrict__ F)
{
  const int gid = blockIdx.x * 256 + threadIdx.x;
  const int lane = threadIdx.x & 63;
  // each 16-lane segment holds cos(phase[0..15]); shuffle per a
  const float cown = cosf(phase[lane & 15]);
  if (blockIdx.x < 1024) {
    // ---- T: 262144 outputs, one per thread, coalesced b-major write ----
    const int p01 = gid >> 10, r = gid & 1023;
    const int b = r >> 6, u = r & 63;
    const int D0 = u >> 3, d1 = u & 7;
    const int i0 = p01 >> 4, i1 = p01 & 15;
    const float* c0 = core0 + i0 * 128 + D0;          // [a] stride 8
    const float* c1 = core1 + i1 * 2048 + b * 8 + d1; // [a] stride 128
    float acc = 0.f;
    #pragma unroll
    for (int a = 0; a < 16; ++a) {
      const float ca = __shfl(cown, a, 16);
      acc += c0[a * 8] * ca * c1[a * 128];
    }
    T[p01 * 1024 + b * 64 + u] = acc;
  } else {
    // ---- F: 65536 outputs, one per thread, coalesced b-major write ----
    const int o = gid - 262144;
    const int p23 = o >> 8, r = o & 255;
    const int b = r >> 4, v = r & 15;
    const int d2 = v >> 2, d3 = v & 3;
    const int i2 = p23 >> 4, i3 = p23 & 15;
    const float* c2 = core2 + i2 * 1024 + b * 64 + d2; // [c] stride 4
    const float* c3 = core3 + i3 * 64 + d3;            // [c] stride 4
    float acc = 0.f;
    #pragma unroll
    for (int c = 0; c < 16; ++c)
      acc += c2[c * 4] * c3[c * 4];
    F[p23 * 256 + b * 16 + v] = acc;
  }
}

__global__ __launch_bounds__(256) void k_out3(
    const int* __restrict__ ids, const float* __restrict__ T,
    const float* __restrict__ F, float* __restrict__ out)
{
  const int wave = threadIdx.x >> 6, lane = threadIdx.x & 63;
  const int n = blockIdx.x * 4 + wave;         // one token per wave
  const int id = ids[n];
  const int p01 = id >> 8, p23 = id & 255;
  const int ug = lane >> 2, vg = lane & 3;     // lane's 4x4 tile: u=4ug+i, v=4vg+j

  const float* __restrict__ Tp = T + p01 * 1024 + ug * 4;  // + b*64
  const float* __restrict__ Fp = F + p23 * 256 + vg * 4;   // + b*16

  float acc[4][4];
  #pragma unroll
  for (int i = 0; i < 4; ++i)
    #pragma unroll
    for (int j = 0; j < 4; ++j) acc[i][j] = 0.f;

  #pragma unroll
  for (int b = 0; b < 16; ++b) {
    // T: 16 segments x 16B contiguous = 256B unique, 4-way broadcast
    const f32x4 t = *reinterpret_cast<const f32x4*>(Tp + b * 64);
    // F: 64B unique, 16-way broadcast
    const f32x4 f = *reinterpret_cast<const f32x4*>(Fp + b * 16);
    acc[0][0] += t.x*f.x; acc[0][1] += t.x*f.y; acc[0][2] += t.x*f.z; acc[0][3] += t.x*f.w;
    acc[1][0] += t.y*f.x; acc[1][1] += t.y*f.y; acc[1][2] += t.y*f.z; acc[1][3] += t.y*f.w;
    acc[2][0] += t.z*f.x; acc[2][1] += t.z*f.y; acc[2][2] += t.z*f.z; acc[2][3] += t.z*f.w;
    acc[3][0] += t.w*f.x; acc[3][1] += t.w*f.y; acc[3][2] += t.w*f.z; acc[3][3] += t.w*f.w;
  }

  // out[n, (4ug+i)*16 + 4vg+j] : 4 store instrs, each 64 lanes x 16B,
  // covering the token's 4KB row in full 64B segments. Nontemporal so the
  // streamed 64MB output doesn't evict the L2-resident T/F tables.
  float* op = out + (size_t)n * 1024 + ug * 64 + vg * 4;
  #pragma unroll
  for (int i = 0; i < 4; ++i) {
    f32x4 v4 = { acc[i][0], acc[i][1], acc[i][2], acc[i][3] };
    __builtin_nontemporal_store(v4, reinterpret_cast<f32x4*>(op + i * 16));
  }
}

extern "C" void kernel_launch(void* const* d_in, const int* in_sizes, int n_in,
                              void* d_out, int out_size, void* d_ws, size_t ws_size,
                              hipStream_t stream) {
  const int*   ids   = (const int*)  d_in[0];
  const float* core0 = (const float*)d_in[1];
  const float* core1 = (const float*)d_in[2];
  const float* core2 = (const float*)d_in[3];
  const float* core3 = (const float*)d_in[4];
  const float* phase = (const float*)d_in[5];
  float* out = (float*)d_out;

  float* Tt = (float*)d_ws;                    // 1 MB
  float* Ft = (float*)d_ws + 256 * 1024;       // 256 KB

  const int tokens = in_sizes[0];              // 16384
  hipLaunchKernelGGL(k_tables, dim3(1280), dim3(256), 0, stream,
                     core0, core1, core2, core3, phase, Tt, Ft);
  hipLaunchKernelGGL(k_out3, dim3(tokens / 4), dim3(256), 0, stream,
                     ids, Tt, Ft, out);
}